// Round 15
// baseline (151.530 us; speedup 1.0000x reference)
//
#include <hip/hip_runtime.h>

#define B_TOT 4096
#define SDIM  1200
#define KPAD  1216   // SDIM padded to multiple of 64 for MFMA K-loop
#define NA    32
#define NH    8
#define EMB   64
#define KHID  128
#define HYP   256
#define NSEL  2048   // NH*HYP
#define NTOT  2560   // NSEL + 256 (wh hid) + 256 (v hid)

// workspace layout (float offsets)
#define WS_H1BF 0                                              // bf16 h1 [B_TOT][NTOT]
#define WS_MBF  (WS_H1BF + (size_t)B_TOT * NTOT / 2)           // bf16 mT [B_TOT][NH][16][8]
#define WS_LG   (WS_MBF  + (size_t)B_TOT * NH * KHID / 2)
#define WS_PART (WS_LG   + (size_t)B_TOT * NH * NA)
#define WS_P2   (WS_PART + (size_t)B_TOT * 16)
#define WS_ABF  (WS_P2   + (size_t)32 * 16)                    // bf16 states [B_TOT][KPAD]
#define WS_WBF  (WS_ABF  + (size_t)B_TOT * KPAD / 2)           // bf16 W1 [NTOT][KPAD]
#define WS_KW32 (WS_WBF  + (size_t)NTOT * KPAD / 2)            // bf16 key_W1[:, :32] [1024][32]
#define WS_B2P  (WS_KW32 + (size_t)1024 * 32 / 2)              // bf16 {w32,b1} [NH][16][8][2]
#define WS_M2T  (WS_B2P  + (size_t)2048 / 2)                   // bf16 M2T [NH][KHID][HYP]

// cvt grid partition
#define CVT_A_BLK 4864   // B_TOT*(KPAD/4)/256
#define CVT_W_BLK 3040   // NTOT*(KPAD/4)/256

typedef __attribute__((ext_vector_type(8))) short short8v;
typedef __attribute__((ext_vector_type(4))) float floatx4;

#define GLL16(gsrc, ldst) __builtin_amdgcn_global_load_lds( \
    (const __attribute__((address_space(1))) unsigned int*)(gsrc), \
    (__attribute__((address_space(3))) unsigned int*)(ldst), 16, 0, 0)

__device__ __forceinline__ ushort f2bf(float x) {
    unsigned u = __builtin_bit_cast(unsigned, x);
    unsigned r = (u + 0x7FFFu + ((u >> 16) & 1u)) >> 16;
    return (ushort)r;
}
__device__ __forceinline__ float bf2f(ushort u) {
    unsigned x = ((unsigned)u) << 16;
    return __builtin_bit_cast(float, x);
}

// ---------------------------------------------------------------------------
// Fused fp32->bf16 conversions (states | W1-concat | key_W1 split + B2p pack).
// ---------------------------------------------------------------------------
__global__ __launch_bounds__(256) void k_cvt_all(
    const float* __restrict__ states, const float* __restrict__ sel_W1,
    const float* __restrict__ wh_W1, const float* __restrict__ v_W1,
    const float* __restrict__ key_W1, const float* __restrict__ key_b1,
    ushort* __restrict__ Abf, ushort* __restrict__ Wbf,
    ushort* __restrict__ kw32, ushort* __restrict__ b2p)
{
    const int gb = blockIdx.x;
    if (gb < CVT_A_BLK) {
        const size_t g = (size_t)gb * 256 + threadIdx.x;
        const int row = (int)(g / (KPAD / 4));
        const int c4  = (int)(g % (KPAD / 4)) * 4;
        ushort4 o = {0, 0, 0, 0};
        if (c4 < SDIM) {
            float4 v = *(const float4*)(states + (size_t)row * SDIM + c4);
            o.x = f2bf(v.x); o.y = f2bf(v.y); o.z = f2bf(v.z); o.w = f2bf(v.w);
        }
        *(ushort4*)(Abf + (size_t)row * KPAD + c4) = o;
    } else if (gb < CVT_A_BLK + CVT_W_BLK) {
        const size_t g = (size_t)(gb - CVT_A_BLK) * 256 + threadIdx.x;
        const int row = (int)(g / (KPAD / 4));
        const int c4  = (int)(g % (KPAD / 4)) * 4;
        const float* src = (row < NSEL)       ? (sel_W1 + (size_t)row * SDIM)
                         : (row < NSEL + HYP) ? (wh_W1 + (size_t)(row - NSEL) * SDIM)
                                              : (v_W1  + (size_t)(row - NSEL - HYP) * SDIM);
        ushort4 o = {0, 0, 0, 0};
        if (c4 < SDIM) {
            float4 v = *(const float4*)(src + c4);
            o.x = f2bf(v.x); o.y = f2bf(v.y); o.z = f2bf(v.z); o.w = f2bf(v.w);
        }
        *(ushort4*)(Wbf + (size_t)row * KPAD + c4) = o;
    } else {
        const int row = (gb - CVT_A_BLK - CVT_W_BLK) * 256 + threadIdx.x;
        if (row >= 1024) return;
        const float* srcr = key_W1 + (size_t)row * 33;
        ushort o[32];
        #pragma unroll
        for (int u = 0; u < 32; ++u) o[u] = f2bf(srcr[u]);
        #pragma unroll
        for (int c = 0; c < 4; ++c)
            *(short8v*)(kw32 + (size_t)row * 32 + c * 8) = *(short8v*)&o[c * 8];
        // B2p pack: [h][k&15][k>>4][{w32,b1}]
        const int h = row >> 7, k = row & 127;
        const size_t po = (((size_t)h * 16 + (k & 15)) * 8 + (k >> 4)) * 2;
        b2p[po]     = f2bf(srcr[32]);
        b2p[po + 1] = f2bf(key_b1[row]);
    }
}

// ---------------------------------------------------------------------------
// M2T[h][k][e] = sum_d sel_W2[h][d][e] * key_W2[h][d][k]  (bf16 out)
// ---------------------------------------------------------------------------
__global__ __launch_bounds__(256) void k_m2(
    const float* __restrict__ sel_W2, const float* __restrict__ key_W2,
    ushort* __restrict__ M2T)
{
    __shared__ float ssel[EMB * HYP];
    __shared__ float skey[EMB][8];
    const int t  = threadIdx.x;
    const int h  = blockIdx.x;
    const int k0 = blockIdx.y * 8;

    const float4* sw = (const float4*)(sel_W2 + (size_t)h * EMB * HYP);
    #pragma unroll
    for (int j = 0; j < 16; ++j)
        ((float4*)ssel)[j * 256 + t] = sw[j * 256 + t];
    if (t < EMB) {
        #pragma unroll
        for (int kk = 0; kk < 8; ++kk)
            skey[t][kk] = key_W2[((size_t)h * EMB + t) * KHID + k0 + kk];
    }
    __syncthreads();

    const int e = t;
    float acc[8] = {};
    for (int d = 0; d < EMB; ++d) {
        const float sv = ssel[d * HYP + e];
        #pragma unroll
        for (int kk = 0; kk < 8; ++kk)
            acc[kk] = fmaf(sv, skey[d][kk], acc[kk]);
    }
    #pragma unroll
    for (int kk = 0; kk < 8; ++kk)
        M2T[((size_t)h * KHID + k0 + kk) * HYP + e] = f2bf(acc[kk]);
}

// ---------------------------------------------------------------------------
// K1: bf16 MFMA GEMM, single-buffered, BK=64 (19 K-steps, 32 MFMA/step),
// XOR chunk-swizzle both-sides. M=4096 N=2560 K=1216, 128x128 tile.
// ---------------------------------------------------------------------------
#define BKG 64
__global__ __launch_bounds__(256) void k_gemm1_mfma(
    const ushort* __restrict__ Abf, const ushort* __restrict__ Wbf,
    const float* __restrict__ sel_b1, const float* __restrict__ wh_b1,
    const float* __restrict__ v_b1, ushort* __restrict__ h1bf)
{
    __shared__ ushort As[128 * BKG];
    __shared__ ushort Bs[128 * BKG];
    const int tid = threadIdx.x;
    const int l   = tid & 63;
    const int w   = tid >> 6;
    const int wM  = w >> 1, wN = w & 1;
    const int arow0 = blockIdx.y * 128;
    const int nrow0 = blockIdx.x * 128;

    const int srow   = tid >> 3;
    const int schunk = tid & 7;
    const int scol   = (schunk ^ (srow & 7)) * 8;
    const ushort* gA = Abf + (size_t)(arow0 + srow) * KPAD + scol;
    const ushort* gB = Wbf + (size_t)(nrow0 + srow) * KPAD + scol;
    ushort* lA = &As[tid * 8];
    ushort* lB = &Bs[tid * 8];

    floatx4 acc[4][4] = {};

    for (int k0 = 0; k0 < KPAD; k0 += BKG) {
        #pragma unroll
        for (int c = 0; c < 4; ++c) {
            GLL16(gA + (size_t)(c * 32) * KPAD + k0, lA + c * 2048);
            GLL16(gB + (size_t)(c * 32) * KPAD + k0, lB + c * 2048);
        }
        __syncthreads();

        #pragma unroll
        for (int kk = 0; kk < 2; ++kk) {
            const int ch = kk * 4 + (l >> 4);
            short8v av[4], bv[4];
            #pragma unroll
            for (int mi = 0; mi < 4; ++mi) {
                const int row = wM * 64 + mi * 16 + (l & 15);
                av[mi] = *(const short8v*)&As[row * BKG + (ch ^ (row & 7)) * 8];
            }
            #pragma unroll
            for (int ni = 0; ni < 4; ++ni) {
                const int row = wN * 64 + ni * 16 + (l & 15);
                bv[ni] = *(const short8v*)&Bs[row * BKG + (ch ^ (row & 7)) * 8];
            }
            #pragma unroll
            for (int mi = 0; mi < 4; ++mi)
                #pragma unroll
                for (int ni = 0; ni < 4; ++ni)
                    acc[mi][ni] = __builtin_amdgcn_mfma_f32_16x16x32_bf16(
                        av[mi], bv[ni], acc[mi][ni], 0, 0, 0);
        }
        __syncthreads();
    }

    float bias_n[4];
    #pragma unroll
    for (int ni = 0; ni < 4; ++ni) {
        const int col = nrow0 + wN * 64 + ni * 16 + (l & 15);
        bias_n[ni] = (col < NSEL)       ? sel_b1[col]
                   : (col < NSEL + HYP) ? wh_b1[col - NSEL]
                                        : v_b1[col - NSEL - HYP];
    }
    #pragma unroll
    for (int mi = 0; mi < 4; ++mi) {
        const int row = arow0 + wM * 64 + mi * 16 + (l >> 4) * 4;
        #pragma unroll
        for (int ni = 0; ni < 4; ++ni) {
            const int col = nrow0 + wN * 64 + ni * 16 + (l & 15);
            #pragma unroll
            for (int r = 0; r < 4; ++r)
                h1bf[(size_t)(row + r) * NTOT + col] =
                    f2bf(fmaxf(acc[mi][ni][r] + bias_n[ni], 0.f));
        }
    }
}

// ---------------------------------------------------------------------------
// K2: per-head m GEMM, dbuf, 64-row tiles. Output mT[b][h][k&15][k>>4].
// ---------------------------------------------------------------------------
#define BK 32
__global__ __launch_bounds__(256) void k_m_mfma(
    const ushort* __restrict__ h1bf, const ushort* __restrict__ M2T,
    ushort* __restrict__ m_out)
{
    __shared__ ushort As[2][64 * BK];
    __shared__ ushort Bs[2][128 * BK];
    const int tid = threadIdx.x;
    const int l   = tid & 63;
    const int w   = tid >> 6;
    const int wM  = w >> 1, wN = w & 1;
    const int h     = blockIdx.x;
    const int brow0 = blockIdx.y * 64;

    const int srow = tid >> 2;
    const int skof = (tid & 3) * 8;
    const ushort* gA = h1bf + (size_t)(brow0 + srow) * NTOT + h * HYP + skof;
    const ushort* gB = M2T + ((size_t)h * KHID + srow) * HYP + skof;

#define STAGE_M(BUF, KK) do { \
    GLL16(gA + (KK), &As[BUF][srow * BK + skof]); \
    GLL16(gB + (KK), &Bs[BUF][srow * BK + skof]); \
    GLL16(gB + (size_t)64 * HYP + (KK), &Bs[BUF][(64 + srow) * BK + skof]); \
} while (0)

    floatx4 acc[2][4] = {};

    STAGE_M(0, 0);
    __syncthreads();
    int cur = 0;
    for (int k0 = 0; k0 < HYP; k0 += BK) {
        if (k0 + BK < HYP) STAGE_M(cur ^ 1, k0 + BK);

        const int kch = (l >> 4) * 8;
        short8v av[2], bv[4];
        #pragma unroll
        for (int mi = 0; mi < 2; ++mi)
            av[mi] = *(const short8v*)&As[cur][(wM * 32 + mi * 16 + (l & 15)) * BK + kch];
        #pragma unroll
        for (int ni = 0; ni < 4; ++ni)
            bv[ni] = *(const short8v*)&Bs[cur][(wN * 64 + ni * 16 + (l & 15)) * BK + kch];
        #pragma unroll
        for (int mi = 0; mi < 2; ++mi)
            #pragma unroll
            for (int ni = 0; ni < 4; ++ni)
                acc[mi][ni] = __builtin_amdgcn_mfma_f32_16x16x32_bf16(
                    av[mi], bv[ni], acc[mi][ni], 0, 0, 0);
        __syncthreads();
        cur ^= 1;
    }

    #pragma unroll
    for (int mi = 0; mi < 2; ++mi) {
        const int row = brow0 + wM * 32 + mi * 16 + (l >> 4) * 4;
        #pragma unroll
        for (int ni = 0; ni < 4; ++ni) {
            const int col = wN * 64 + ni * 16 + (l & 15);
            #pragma unroll
            for (int r = 0; r < 4; ++r)
                m_out[(((size_t)(row + r) * NH + h) * 16 + (col & 15)) * 8 + (col >> 4)]
                    = f2bf(acc[mi][ni][r]);
        }
    }
}

// ---------------------------------------------------------------------------
// K3: logits — barrier-free, LDS-free. Wave = (batch, 4-head half), head
// loop NOT unrolled (keeps VGPR low -> 5-6 resident waves/SIMD). 8192 waves.
// logits[b,h,a] = sum_k relu(U32.W[h,k] + q*w32[h,k] + b1[h,k]) * m[b,h,k]
// ---------------------------------------------------------------------------
__global__ __launch_bounds__(256, 5) void k_logits_mfma(
    const ushort* __restrict__ Abf, const ushort* __restrict__ KW32,
    const ushort* __restrict__ B2p, const float* __restrict__ agent_qs,
    const ushort* __restrict__ mT, float* __restrict__ logits)
{
    const int tid = threadIdx.x;
    const int l   = tid & 63;
    const int w   = tid >> 6;
    const int wid = blockIdx.x * 4 + w;
    const int b   = wid >> 1;
    const int h0  = (wid & 1) * 4;

    short8v av[2];
    float4 qv[2];
    #pragma unroll
    for (int mi = 0; mi < 2; ++mi) {
        const int a = mi * 16 + (l & 15);
        av[mi] = *(const short8v*)(
            Abf + (size_t)b * KPAD + a * 32 + (l >> 4) * 8);
        qv[mi] = *(const float4*)(
            agent_qs + (size_t)b * NA + mi * 16 + (l >> 4) * 4);
    }

    #pragma clang loop unroll(disable)
    for (int hh = 0; hh < 4; ++hh) {
        const int h = h0 + hh;
        // packed {w32,b1}: 16 ushorts for this lane's column set
        const int bpo = (h * 16 + (l & 15)) * 16;
        short8v wb0 = *(const short8v*)&B2p[bpo];
        short8v wb1 = *(const short8v*)&B2p[bpo + 8];
        short8v bv[8];
        #pragma unroll
        for (int ni = 0; ni < 8; ++ni) {
            const int k = ni * 16 + (l & 15);
            bv[ni] = *(const short8v*)(
                KW32 + ((size_t)h * KHID + k) * 32 + (l >> 4) * 8);
        }
        short8v mv = *(const short8v*)(
            mT + (((size_t)b * NH + h) * 16 + (l & 15)) * 8);
        float mr[8], w32r[8], b1r[8];
        #pragma unroll
        for (int ni = 0; ni < 8; ++ni) {
            mr[ni]   = bf2f((ushort)mv[ni]);
            w32r[ni] = bf2f((ushort)((ni < 4) ? wb0[ni * 2]       : wb1[(ni - 4) * 2]));
            b1r[ni]  = bf2f((ushort)((ni < 4) ? wb0[ni * 2 + 1]   : wb1[(ni - 4) * 2 + 1]));
        }

        floatx4 acc[2][8] = {};
        __builtin_amdgcn_s_setprio(1);
        #pragma unroll
        for (int mi = 0; mi < 2; ++mi)
            #pragma unroll
            for (int ni = 0; ni < 8; ++ni)
                acc[mi][ni] = __builtin_amdgcn_mfma_f32_16x16x32_bf16(
                    av[mi], bv[ni], acc[mi][ni], 0, 0, 0);
        __builtin_amdgcn_s_setprio(0);

        #pragma unroll
        for (int mi = 0; mi < 2; ++mi) {
            float s0 = 0.f, s1 = 0.f, s2 = 0.f, s3 = 0.f;
            #pragma unroll
            for (int ni = 0; ni < 8; ++ni) {
                const float b1v = b1r[ni], wv = w32r[ni], mv2 = mr[ni];
                s0 = fmaf(fmaxf(fmaf(qv[mi].x, wv, acc[mi][ni][0] + b1v), 0.f), mv2, s0);
                s1 = fmaf(fmaxf(fmaf(qv[mi].y, wv, acc[mi][ni][1] + b1v), 0.f), mv2, s1);
                s2 = fmaf(fmaxf(fmaf(qv[mi].z, wv, acc[mi][ni][2] + b1v), 0.f), mv2, s2);
                s3 = fmaf(fmaxf(fmaf(qv[mi].w, wv, acc[mi][ni][3] + b1v), 0.f), mv2, s3);
            }
            #pragma unroll
            for (int off = 8; off >= 1; off >>= 1) {
                s0 += __shfl_xor(s0, off);
                s1 += __shfl_xor(s1, off);
                s2 += __shfl_xor(s2, off);
                s3 += __shfl_xor(s3, off);
            }
            if ((l & 15) == 0) {
                float4 o = {s0, s1, s2, s3};
                *(float4*)(logits + ((size_t)b * NH + h) * NA
                           + mi * 16 + (l >> 4) * 4) = o;
            }
        }
    }
}

// ---------------------------------------------------------------------------
// K4: wh/v second layers + masked softmax + head_q + final mix.
// ---------------------------------------------------------------------------
__global__ __launch_bounds__(256) void k_softmax(
    const float* __restrict__ logits, const float* __restrict__ agent_qs,
    const int* __restrict__ actions, const ushort* __restrict__ h1bf,
    const float* __restrict__ wh_W2, const float* __restrict__ wh_b2,
    const float* __restrict__ v_W2, const float* __restrict__ v_b2,
    float* __restrict__ out, float* __restrict__ part)
{
    __shared__ float qs[NA];
    __shared__ int   act_s[NA];
    __shared__ float whs[NH];
    __shared__ float hq[NH];
    __shared__ float vred[4];
    const int b = blockIdx.x, t = threadIdx.x;
    if (t < NA) {
        qs[t]    = agent_qs[(size_t)b * NA + t];
        act_s[t] = actions[(size_t)b * NA + t];
    }
    const int h = t >> 5, a = t & 31;
    {
        float acc = 0.f;
        #pragma unroll
        for (int j = 0; j < 8; ++j) {
            const int e = a + 32 * j;
            acc = fmaf(bf2f(h1bf[(size_t)b * NTOT + NSEL + e]),
                       wh_W2[h * HYP + e], acc);
        }
        #pragma unroll
        for (int off = 16; off >= 1; off >>= 1) acc += __shfl_xor(acc, off, 32);
        if (a == 0) whs[h] = fabsf(acc + wh_b2[h]);
    }
    {
        float acc = bf2f(h1bf[(size_t)b * NTOT + NSEL + HYP + t]) * v_W2[t];
        #pragma unroll
        for (int off = 32; off >= 1; off >>= 1) acc += __shfl_xor(acc, off);
        if ((t & 63) == 0) vred[t >> 6] = acc;
    }
    __syncthreads();

    const float lg = logits[((size_t)b * NH + h) * NA + a];
    float sc = (act_s[a] == 0) ? -99999999.0f : lg * 0.125f;

    float mx = sc;
    #pragma unroll
    for (int off = 16; off >= 1; off >>= 1) mx = fmaxf(mx, __shfl_xor(mx, off, 32));
    const float e = expf(sc - mx);
    float sum = e;
    #pragma unroll
    for (int off = 16; off >= 1; off >>= 1) sum += __shfl_xor(sum, off, 32);
    const float wgt = e / sum;

    float r_sq  = lg * lg;
    float r_hq  = qs[a] * wgt;
    float r_ent = -wgt * logf(wgt + 1e-8f);
    #pragma unroll
    for (int off = 16; off >= 1; off >>= 1) {
        r_sq  += __shfl_xor(r_sq,  off, 32);
        r_hq  += __shfl_xor(r_hq,  off, 32);
        r_ent += __shfl_xor(r_ent, off, 32);
    }
    if (a == 0) {
        hq[h] = r_hq;
        part[(size_t)b * 16 + h]     = r_sq;
        part[(size_t)b * 16 + 8 + h] = r_ent;
    }
    __syncthreads();
    if (t == 0) {
        float y = vred[0] + vred[1] + vred[2] + vred[3] + v_b2[0];
        #pragma unroll
        for (int i = 0; i < NH; ++i) y = fmaf(whs[i], hq[i], y);
        out[b] = y;
    }
}

// ---------------------------------------------------------------------------
// K5a/K5b: two-stage partials reduction.
// ---------------------------------------------------------------------------
__global__ __launch_bounds__(256) void k_final_s1(
    const float* __restrict__ part, float* __restrict__ part2)
{
    __shared__ float red[16][17];
    const int t = threadIdx.x;
    const int c = t & 15, rl = t >> 4;
    const int rbase = blockIdx.x * 128 + rl;
    float v0 = 0.f, v1 = 0.f, v2 = 0.f, v3 = 0.f;
    #pragma unroll
    for (int j = 0; j < 8; j += 4) {
        v0 += part[(size_t)(rbase + (j + 0) * 16) * 16 + c];
        v1 += part[(size_t)(rbase + (j + 1) * 16) * 16 + c];
        v2 += part[(size_t)(rbase + (j + 2) * 16) * 16 + c];
        v3 += part[(size_t)(rbase + (j + 3) * 16) * 16 + c];
    }
    red[rl][c] = (v0 + v1) + (v2 + v3);
    __syncthreads();
    if (t < 16) {
        float s = 0.f;
        #pragma unroll
        for (int i = 0; i < 16; ++i) s += red[i][t];
        part2[blockIdx.x * 16 + t] = s;
    }
}

__global__ __launch_bounds__(256) void k_final_s2(
    const float* __restrict__ part2, float* __restrict__ out)
{
    __shared__ float red[16][17];
    __shared__ float tot[16];
    const int t = threadIdx.x;
    {
        const int g = t >> 4, c = t & 15;
        red[g][c] = part2[t] + part2[t + 256];
    }
    __syncthreads();
    if (t < 16) {
        float s = 0.f;
        #pragma unroll
        for (int i = 0; i < 16; ++i) s += red[i][t];
        tot[t] = s;
    }
    __syncthreads();
    if (t == 0) {
        float s = 0.f;
        #pragma unroll
        for (int i = 0; i < 8; ++i) s += tot[i];
        out[B_TOT] = 0.001f * (s / (float)((size_t)B_TOT * NA));
    }
    if (t >= 8 && t < 16)
        out[B_TOT + 1 + (t - 8)] = tot[t] / (float)B_TOT;
}

extern "C" void kernel_launch(void* const* d_in, const int* in_sizes, int n_in,
                              void* d_out, int out_size, void* d_ws, size_t ws_size,
                              hipStream_t stream) {
    (void)in_sizes; (void)n_in; (void)out_size; (void)ws_size;
    const float* agent_qs = (const float*)d_in[0];
    const float* states   = (const float*)d_in[1];
    const int*   actions  = (const int*)d_in[2];
    const float* sel_W1   = (const float*)d_in[3];
    const float* sel_b1   = (const float*)d_in[4];
    const float* sel_W2   = (const float*)d_in[5];
    const float* key_W1   = (const float*)d_in[6];
    const float* key_b1   = (const float*)d_in[7];
    const float* key_W2   = (const float*)d_in[8];
    const float* wh_W1    = (const float*)d_in[9];
    const float* wh_b1    = (const float*)d_in[10];
    const float* wh_W2    = (const float*)d_in[11];
    const float* wh_b2    = (const float*)d_in[12];
    const float* v_W1     = (const float*)d_in[13];
    const float* v_b1     = (const float*)d_in[14];
    const float* v_W2     = (const float*)d_in[15];
    const float* v_b2     = (const float*)d_in[16];

    float* out = (float*)d_out;
    float* ws  = (float*)d_ws;
    ushort* h1bf  = (ushort*)(ws + WS_H1BF);
    ushort* m_buf = (ushort*)(ws + WS_MBF);
    float* lg_buf = ws + WS_LG;
    float* part   = ws + WS_PART;
    float* part2  = ws + WS_P2;
    ushort* Abf   = (ushort*)(ws + WS_ABF);
    ushort* Wbf   = (ushort*)(ws + WS_WBF);
    ushort* KW32  = (ushort*)(ws + WS_KW32);
    ushort* B2p   = (ushort*)(ws + WS_B2P);
    ushort* M2T   = (ushort*)(ws + WS_M2T);

    k_cvt_all<<<CVT_A_BLK + CVT_W_BLK + 4, 256, 0, stream>>>(
        states, sel_W1, wh_W1, v_W1, key_W1, key_b1, Abf, Wbf, KW32, B2p);
    k_m2<<<dim3(NH, KHID / 8), 256, 0, stream>>>(sel_W2, key_W2, M2T);
    k_gemm1_mfma<<<dim3(NTOT / 128, B_TOT / 128), 256, 0, stream>>>(
        Abf, Wbf, sel_b1, wh_b1, v_b1, h1bf);
    k_m_mfma<<<dim3(NH, B_TOT / 64), 256, 0, stream>>>(h1bf, M2T, m_buf);
    k_logits_mfma<<<dim3(B_TOT / 2), 256, 0, stream>>>(
        Abf, KW32, B2p, agent_qs, m_buf, lg_buf);
    k_softmax<<<dim3(B_TOT), 256, 0, stream>>>(
        lg_buf, agent_qs, actions, h1bf, wh_W2, wh_b2, v_W2, v_b2, out, part);
    k_final_s1<<<32, 256, 0, stream>>>(part, part2);
    k_final_s2<<<1, 256, 0, stream>>>(part2, out);
}

// Round 16
// 109.298 us; speedup vs baseline: 1.3864x; 1.3864x over previous
//
#include <hip/hip_runtime.h>

#define B_TOT 4096
#define SDIM  1200
#define KPAD  1216   // SDIM padded to multiple of 64 for MFMA K-loop
#define NA    32
#define NH    8
#define EMB   64
#define KHID  128
#define HYP   256
#define NSEL  2048   // NH*HYP
#define NTOT  2560   // NSEL + 256 (wh hid) + 256 (v hid)

// workspace layout (float offsets)
#define WS_H1BF 0                                              // bf16 h1 [B_TOT][NTOT]
#define WS_MBF  (WS_H1BF + (size_t)B_TOT * NTOT / 2)           // bf16 mT [B_TOT][NH][16][8]
#define WS_LG   (WS_MBF  + (size_t)B_TOT * NH * KHID / 2)
#define WS_PART (WS_LG   + (size_t)B_TOT * NH * NA)
#define WS_P2   (WS_PART + (size_t)B_TOT * 16)
#define WS_ABF  (WS_P2   + (size_t)32 * 16)                    // bf16 states [B_TOT][KPAD]
#define WS_WBF  (WS_ABF  + (size_t)B_TOT * KPAD / 2)           // bf16 W1 [NTOT][KPAD]
#define WS_KW32 (WS_WBF  + (size_t)NTOT * KPAD / 2)            // bf16 key_W1[:, :32] [1024][32]
#define WS_B2P  (WS_KW32 + (size_t)1024 * 32 / 2)              // bf16 {w32,b1} [NH][16][8][2]
#define WS_M2T  (WS_B2P  + (size_t)2048 / 2)                   // bf16 M2T [NH][KHID][HYP]

// cvt grid partition
#define CVT_A_BLK 4864   // B_TOT*(KPAD/4)/256
#define CVT_W_BLK 3040   // NTOT*(KPAD/4)/256

typedef __attribute__((ext_vector_type(8))) short short8v;
typedef __attribute__((ext_vector_type(4))) float floatx4;

#define GLL16(gsrc, ldst) __builtin_amdgcn_global_load_lds( \
    (const __attribute__((address_space(1))) unsigned int*)(gsrc), \
    (__attribute__((address_space(3))) unsigned int*)(ldst), 16, 0, 0)

__device__ __forceinline__ ushort f2bf(float x) {
    unsigned u = __builtin_bit_cast(unsigned, x);
    unsigned r = (u + 0x7FFFu + ((u >> 16) & 1u)) >> 16;
    return (ushort)r;
}
__device__ __forceinline__ float bf2f(ushort u) {
    unsigned x = ((unsigned)u) << 16;
    return __builtin_bit_cast(float, x);
}

// ---------------------------------------------------------------------------
// Fused fp32->bf16 conversions (states | W1-concat | key_W1 split + B2p pack).
// ---------------------------------------------------------------------------
__global__ __launch_bounds__(256) void k_cvt_all(
    const float* __restrict__ states, const float* __restrict__ sel_W1,
    const float* __restrict__ wh_W1, const float* __restrict__ v_W1,
    const float* __restrict__ key_W1, const float* __restrict__ key_b1,
    ushort* __restrict__ Abf, ushort* __restrict__ Wbf,
    ushort* __restrict__ kw32, ushort* __restrict__ b2p)
{
    const int gb = blockIdx.x;
    if (gb < CVT_A_BLK) {
        const size_t g = (size_t)gb * 256 + threadIdx.x;
        const int row = (int)(g / (KPAD / 4));
        const int c4  = (int)(g % (KPAD / 4)) * 4;
        ushort4 o = {0, 0, 0, 0};
        if (c4 < SDIM) {
            float4 v = *(const float4*)(states + (size_t)row * SDIM + c4);
            o.x = f2bf(v.x); o.y = f2bf(v.y); o.z = f2bf(v.z); o.w = f2bf(v.w);
        }
        *(ushort4*)(Abf + (size_t)row * KPAD + c4) = o;
    } else if (gb < CVT_A_BLK + CVT_W_BLK) {
        const size_t g = (size_t)(gb - CVT_A_BLK) * 256 + threadIdx.x;
        const int row = (int)(g / (KPAD / 4));
        const int c4  = (int)(g % (KPAD / 4)) * 4;
        const float* src = (row < NSEL)       ? (sel_W1 + (size_t)row * SDIM)
                         : (row < NSEL + HYP) ? (wh_W1 + (size_t)(row - NSEL) * SDIM)
                                              : (v_W1  + (size_t)(row - NSEL - HYP) * SDIM);
        ushort4 o = {0, 0, 0, 0};
        if (c4 < SDIM) {
            float4 v = *(const float4*)(src + c4);
            o.x = f2bf(v.x); o.y = f2bf(v.y); o.z = f2bf(v.z); o.w = f2bf(v.w);
        }
        *(ushort4*)(Wbf + (size_t)row * KPAD + c4) = o;
    } else {
        const int row = (gb - CVT_A_BLK - CVT_W_BLK) * 256 + threadIdx.x;
        if (row >= 1024) return;
        const float* srcr = key_W1 + (size_t)row * 33;
        ushort o[32];
        #pragma unroll
        for (int u = 0; u < 32; ++u) o[u] = f2bf(srcr[u]);
        #pragma unroll
        for (int c = 0; c < 4; ++c)
            *(short8v*)(kw32 + (size_t)row * 32 + c * 8) = *(short8v*)&o[c * 8];
        // B2p pack: [h][k&15][k>>4][{w32,b1}]
        const int h = row >> 7, k = row & 127;
        const size_t po = (((size_t)h * 16 + (k & 15)) * 8 + (k >> 4)) * 2;
        b2p[po]     = f2bf(srcr[32]);
        b2p[po + 1] = f2bf(key_b1[row]);
    }
}

// ---------------------------------------------------------------------------
// M2T[h][k][e] = sum_d sel_W2[h][d][e] * key_W2[h][d][k]  (bf16 out)
// ---------------------------------------------------------------------------
__global__ __launch_bounds__(256) void k_m2(
    const float* __restrict__ sel_W2, const float* __restrict__ key_W2,
    ushort* __restrict__ M2T)
{
    __shared__ float ssel[EMB * HYP];
    __shared__ float skey[EMB][8];
    const int t  = threadIdx.x;
    const int h  = blockIdx.x;
    const int k0 = blockIdx.y * 8;

    const float4* sw = (const float4*)(sel_W2 + (size_t)h * EMB * HYP);
    #pragma unroll
    for (int j = 0; j < 16; ++j)
        ((float4*)ssel)[j * 256 + t] = sw[j * 256 + t];
    if (t < EMB) {
        #pragma unroll
        for (int kk = 0; kk < 8; ++kk)
            skey[t][kk] = key_W2[((size_t)h * EMB + t) * KHID + k0 + kk];
    }
    __syncthreads();

    const int e = t;
    float acc[8] = {};
    for (int d = 0; d < EMB; ++d) {
        const float sv = ssel[d * HYP + e];
        #pragma unroll
        for (int kk = 0; kk < 8; ++kk)
            acc[kk] = fmaf(sv, skey[d][kk], acc[kk]);
    }
    #pragma unroll
    for (int kk = 0; kk < 8; ++kk)
        M2T[((size_t)h * KHID + k0 + kk) * HYP + e] = f2bf(acc[kk]);
}

// ---------------------------------------------------------------------------
// K1: bf16 MFMA GEMM, single-buffered, BK=64 (19 K-steps, 32 MFMA/step),
// XOR chunk-swizzle both-sides. M=4096 N=2560 K=1216, 128x128 tile.
// ---------------------------------------------------------------------------
#define BKG 64
__global__ __launch_bounds__(256) void k_gemm1_mfma(
    const ushort* __restrict__ Abf, const ushort* __restrict__ Wbf,
    const float* __restrict__ sel_b1, const float* __restrict__ wh_b1,
    const float* __restrict__ v_b1, ushort* __restrict__ h1bf)
{
    __shared__ ushort As[128 * BKG];
    __shared__ ushort Bs[128 * BKG];
    const int tid = threadIdx.x;
    const int l   = tid & 63;
    const int w   = tid >> 6;
    const int wM  = w >> 1, wN = w & 1;
    const int arow0 = blockIdx.y * 128;
    const int nrow0 = blockIdx.x * 128;

    const int srow   = tid >> 3;
    const int schunk = tid & 7;
    const int scol   = (schunk ^ (srow & 7)) * 8;
    const ushort* gA = Abf + (size_t)(arow0 + srow) * KPAD + scol;
    const ushort* gB = Wbf + (size_t)(nrow0 + srow) * KPAD + scol;
    ushort* lA = &As[tid * 8];
    ushort* lB = &Bs[tid * 8];

    floatx4 acc[4][4] = {};

    for (int k0 = 0; k0 < KPAD; k0 += BKG) {
        #pragma unroll
        for (int c = 0; c < 4; ++c) {
            GLL16(gA + (size_t)(c * 32) * KPAD + k0, lA + c * 2048);
            GLL16(gB + (size_t)(c * 32) * KPAD + k0, lB + c * 2048);
        }
        __syncthreads();

        #pragma unroll
        for (int kk = 0; kk < 2; ++kk) {
            const int ch = kk * 4 + (l >> 4);
            short8v av[4], bv[4];
            #pragma unroll
            for (int mi = 0; mi < 4; ++mi) {
                const int row = wM * 64 + mi * 16 + (l & 15);
                av[mi] = *(const short8v*)&As[row * BKG + (ch ^ (row & 7)) * 8];
            }
            #pragma unroll
            for (int ni = 0; ni < 4; ++ni) {
                const int row = wN * 64 + ni * 16 + (l & 15);
                bv[ni] = *(const short8v*)&Bs[row * BKG + (ch ^ (row & 7)) * 8];
            }
            #pragma unroll
            for (int mi = 0; mi < 4; ++mi)
                #pragma unroll
                for (int ni = 0; ni < 4; ++ni)
                    acc[mi][ni] = __builtin_amdgcn_mfma_f32_16x16x32_bf16(
                        av[mi], bv[ni], acc[mi][ni], 0, 0, 0);
        }
        __syncthreads();
    }

    float bias_n[4];
    #pragma unroll
    for (int ni = 0; ni < 4; ++ni) {
        const int col = nrow0 + wN * 64 + ni * 16 + (l & 15);
        bias_n[ni] = (col < NSEL)       ? sel_b1[col]
                   : (col < NSEL + HYP) ? wh_b1[col - NSEL]
                                        : v_b1[col - NSEL - HYP];
    }
    #pragma unroll
    for (int mi = 0; mi < 4; ++mi) {
        const int row = arow0 + wM * 64 + mi * 16 + (l >> 4) * 4;
        #pragma unroll
        for (int ni = 0; ni < 4; ++ni) {
            const int col = nrow0 + wN * 64 + ni * 16 + (l & 15);
            #pragma unroll
            for (int r = 0; r < 4; ++r)
                h1bf[(size_t)(row + r) * NTOT + col] =
                    f2bf(fmaxf(acc[mi][ni][r] + bias_n[ni], 0.f));
        }
    }
}

// ---------------------------------------------------------------------------
// K2: per-head m GEMM, dbuf, 64-row tiles. Output mT[b][h][k&15][k>>4].
// ---------------------------------------------------------------------------
#define BK 32
__global__ __launch_bounds__(256) void k_m_mfma(
    const ushort* __restrict__ h1bf, const ushort* __restrict__ M2T,
    ushort* __restrict__ m_out)
{
    __shared__ ushort As[2][64 * BK];
    __shared__ ushort Bs[2][128 * BK];
    const int tid = threadIdx.x;
    const int l   = tid & 63;
    const int w   = tid >> 6;
    const int wM  = w >> 1, wN = w & 1;
    const int h     = blockIdx.x;
    const int brow0 = blockIdx.y * 64;

    const int srow = tid >> 2;
    const int skof = (tid & 3) * 8;
    const ushort* gA = h1bf + (size_t)(brow0 + srow) * NTOT + h * HYP + skof;
    const ushort* gB = M2T + ((size_t)h * KHID + srow) * HYP + skof;

#define STAGE_M(BUF, KK) do { \
    GLL16(gA + (KK), &As[BUF][srow * BK + skof]); \
    GLL16(gB + (KK), &Bs[BUF][srow * BK + skof]); \
    GLL16(gB + (size_t)64 * HYP + (KK), &Bs[BUF][(64 + srow) * BK + skof]); \
} while (0)

    floatx4 acc[2][4] = {};

    STAGE_M(0, 0);
    __syncthreads();
    int cur = 0;
    for (int k0 = 0; k0 < HYP; k0 += BK) {
        if (k0 + BK < HYP) STAGE_M(cur ^ 1, k0 + BK);

        const int kch = (l >> 4) * 8;
        short8v av[2], bv[4];
        #pragma unroll
        for (int mi = 0; mi < 2; ++mi)
            av[mi] = *(const short8v*)&As[cur][(wM * 32 + mi * 16 + (l & 15)) * BK + kch];
        #pragma unroll
        for (int ni = 0; ni < 4; ++ni)
            bv[ni] = *(const short8v*)&Bs[cur][(wN * 64 + ni * 16 + (l & 15)) * BK + kch];
        #pragma unroll
        for (int mi = 0; mi < 2; ++mi)
            #pragma unroll
            for (int ni = 0; ni < 4; ++ni)
                acc[mi][ni] = __builtin_amdgcn_mfma_f32_16x16x32_bf16(
                    av[mi], bv[ni], acc[mi][ni], 0, 0, 0);
        __syncthreads();
        cur ^= 1;
    }

    #pragma unroll
    for (int mi = 0; mi < 2; ++mi) {
        const int row = brow0 + wM * 32 + mi * 16 + (l >> 4) * 4;
        #pragma unroll
        for (int ni = 0; ni < 4; ++ni) {
            const int col = wN * 64 + ni * 16 + (l & 15);
            #pragma unroll
            for (int r = 0; r < 4; ++r)
                m_out[(((size_t)(row + r) * NH + h) * 16 + (col & 15)) * 8 + (col >> 4)]
                    = f2bf(acc[mi][ni][r]);
        }
    }
}

// ---------------------------------------------------------------------------
// K3: logits — R10 structure verbatim (1 wave = 1 batch, plain 8-head loop,
// barrier-free, LDS-free, no pragmas). Only changes vs R10: m via one 16B
// mT load (was 8 scalars) and w32/b1 via two 16B B2p loads (was 16 scalars).
// logits[b,h,a] = sum_k relu(U32.W[h,k] + q*w32[h,k] + b1[h,k]) * m[b,h,k]
// ---------------------------------------------------------------------------
__global__ __launch_bounds__(256) void k_logits_mfma(
    const ushort* __restrict__ Abf, const ushort* __restrict__ KW32,
    const ushort* __restrict__ B2p, const float* __restrict__ agent_qs,
    const ushort* __restrict__ mT, float* __restrict__ logits)
{
    const int tid = threadIdx.x;
    const int l   = tid & 63;
    const int w   = tid >> 6;
    const int b   = blockIdx.x * 4 + w;

    short8v av[2];
    float4 qv[2];
    #pragma unroll
    for (int mi = 0; mi < 2; ++mi) {
        const int a = mi * 16 + (l & 15);
        av[mi] = *(const short8v*)(
            Abf + (size_t)b * KPAD + a * 32 + (l >> 4) * 8);
        qv[mi] = *(const float4*)(
            agent_qs + (size_t)b * NA + mi * 16 + (l >> 4) * 4);
    }

    for (int h = 0; h < NH; ++h) {
        short8v bv[8];
        #pragma unroll
        for (int ni = 0; ni < 8; ++ni) {
            const int k = ni * 16 + (l & 15);
            bv[ni] = *(const short8v*)(
                KW32 + ((size_t)h * KHID + k) * 32 + (l >> 4) * 8);
        }
        const int bpo = (h * 16 + (l & 15)) * 16;
        short8v wb0 = *(const short8v*)&B2p[bpo];
        short8v wb1 = *(const short8v*)&B2p[bpo + 8];
        short8v mv = *(const short8v*)(
            mT + (((size_t)b * NH + h) * 16 + (l & 15)) * 8);
        float mr[8], w32r[8], b1r[8];
        #pragma unroll
        for (int ni = 0; ni < 8; ++ni) {
            mr[ni]   = bf2f((ushort)mv[ni]);
            w32r[ni] = bf2f((ushort)((ni < 4) ? wb0[ni * 2]     : wb1[(ni - 4) * 2]));
            b1r[ni]  = bf2f((ushort)((ni < 4) ? wb0[ni * 2 + 1] : wb1[(ni - 4) * 2 + 1]));
        }

        floatx4 acc[2][8] = {};
        #pragma unroll
        for (int mi = 0; mi < 2; ++mi)
            #pragma unroll
            for (int ni = 0; ni < 8; ++ni)
                acc[mi][ni] = __builtin_amdgcn_mfma_f32_16x16x32_bf16(
                    av[mi], bv[ni], acc[mi][ni], 0, 0, 0);

        #pragma unroll
        for (int mi = 0; mi < 2; ++mi) {
            float s0 = 0.f, s1 = 0.f, s2 = 0.f, s3 = 0.f;
            #pragma unroll
            for (int ni = 0; ni < 8; ++ni) {
                const float b1v = b1r[ni], wv = w32r[ni], mv2 = mr[ni];
                s0 = fmaf(fmaxf(fmaf(qv[mi].x, wv, acc[mi][ni][0] + b1v), 0.f), mv2, s0);
                s1 = fmaf(fmaxf(fmaf(qv[mi].y, wv, acc[mi][ni][1] + b1v), 0.f), mv2, s1);
                s2 = fmaf(fmaxf(fmaf(qv[mi].z, wv, acc[mi][ni][2] + b1v), 0.f), mv2, s2);
                s3 = fmaf(fmaxf(fmaf(qv[mi].w, wv, acc[mi][ni][3] + b1v), 0.f), mv2, s3);
            }
            #pragma unroll
            for (int off = 8; off >= 1; off >>= 1) {
                s0 += __shfl_xor(s0, off);
                s1 += __shfl_xor(s1, off);
                s2 += __shfl_xor(s2, off);
                s3 += __shfl_xor(s3, off);
            }
            if ((l & 15) == 0) {
                float4 o = {s0, s1, s2, s3};
                *(float4*)(logits + ((size_t)b * NH + h) * NA
                           + mi * 16 + (l >> 4) * 4) = o;
            }
        }
    }
}

// ---------------------------------------------------------------------------
// K4: wh/v second layers + masked softmax + head_q + final mix.
// ---------------------------------------------------------------------------
__global__ __launch_bounds__(256) void k_softmax(
    const float* __restrict__ logits, const float* __restrict__ agent_qs,
    const int* __restrict__ actions, const ushort* __restrict__ h1bf,
    const float* __restrict__ wh_W2, const float* __restrict__ wh_b2,
    const float* __restrict__ v_W2, const float* __restrict__ v_b2,
    float* __restrict__ out, float* __restrict__ part)
{
    __shared__ float qs[NA];
    __shared__ int   act_s[NA];
    __shared__ float whs[NH];
    __shared__ float hq[NH];
    __shared__ float vred[4];
    const int b = blockIdx.x, t = threadIdx.x;
    if (t < NA) {
        qs[t]    = agent_qs[(size_t)b * NA + t];
        act_s[t] = actions[(size_t)b * NA + t];
    }
    const int h = t >> 5, a = t & 31;
    {
        float acc = 0.f;
        #pragma unroll
        for (int j = 0; j < 8; ++j) {
            const int e = a + 32 * j;
            acc = fmaf(bf2f(h1bf[(size_t)b * NTOT + NSEL + e]),
                       wh_W2[h * HYP + e], acc);
        }
        #pragma unroll
        for (int off = 16; off >= 1; off >>= 1) acc += __shfl_xor(acc, off, 32);
        if (a == 0) whs[h] = fabsf(acc + wh_b2[h]);
    }
    {
        float acc = bf2f(h1bf[(size_t)b * NTOT + NSEL + HYP + t]) * v_W2[t];
        #pragma unroll
        for (int off = 32; off >= 1; off >>= 1) acc += __shfl_xor(acc, off);
        if ((t & 63) == 0) vred[t >> 6] = acc;
    }
    __syncthreads();

    const float lg = logits[((size_t)b * NH + h) * NA + a];
    float sc = (act_s[a] == 0) ? -99999999.0f : lg * 0.125f;

    float mx = sc;
    #pragma unroll
    for (int off = 16; off >= 1; off >>= 1) mx = fmaxf(mx, __shfl_xor(mx, off, 32));
    const float e = expf(sc - mx);
    float sum = e;
    #pragma unroll
    for (int off = 16; off >= 1; off >>= 1) sum += __shfl_xor(sum, off, 32);
    const float wgt = e / sum;

    float r_sq  = lg * lg;
    float r_hq  = qs[a] * wgt;
    float r_ent = -wgt * logf(wgt + 1e-8f);
    #pragma unroll
    for (int off = 16; off >= 1; off >>= 1) {
        r_sq  += __shfl_xor(r_sq,  off, 32);
        r_hq  += __shfl_xor(r_hq,  off, 32);
        r_ent += __shfl_xor(r_ent, off, 32);
    }
    if (a == 0) {
        hq[h] = r_hq;
        part[(size_t)b * 16 + h]     = r_sq;
        part[(size_t)b * 16 + 8 + h] = r_ent;
    }
    __syncthreads();
    if (t == 0) {
        float y = vred[0] + vred[1] + vred[2] + vred[3] + v_b2[0];
        #pragma unroll
        for (int i = 0; i < NH; ++i) y = fmaf(whs[i], hq[i], y);
        out[b] = y;
    }
}

// ---------------------------------------------------------------------------
// K5a/K5b: two-stage partials reduction.
// ---------------------------------------------------------------------------
__global__ __launch_bounds__(256) void k_final_s1(
    const float* __restrict__ part, float* __restrict__ part2)
{
    __shared__ float red[16][17];
    const int t = threadIdx.x;
    const int c = t & 15, rl = t >> 4;
    const int rbase = blockIdx.x * 128 + rl;
    float v0 = 0.f, v1 = 0.f, v2 = 0.f, v3 = 0.f;
    #pragma unroll
    for (int j = 0; j < 8; j += 4) {
        v0 += part[(size_t)(rbase + (j + 0) * 16) * 16 + c];
        v1 += part[(size_t)(rbase + (j + 1) * 16) * 16 + c];
        v2 += part[(size_t)(rbase + (j + 2) * 16) * 16 + c];
        v3 += part[(size_t)(rbase + (j + 3) * 16) * 16 + c];
    }
    red[rl][c] = (v0 + v1) + (v2 + v3);
    __syncthreads();
    if (t < 16) {
        float s = 0.f;
        #pragma unroll
        for (int i = 0; i < 16; ++i) s += red[i][t];
        part2[blockIdx.x * 16 + t] = s;
    }
}

__global__ __launch_bounds__(256) void k_final_s2(
    const float* __restrict__ part2, float* __restrict__ out)
{
    __shared__ float red[16][17];
    __shared__ float tot[16];
    const int t = threadIdx.x;
    {
        const int g = t >> 4, c = t & 15;
        red[g][c] = part2[t] + part2[t + 256];
    }
    __syncthreads();
    if (t < 16) {
        float s = 0.f;
        #pragma unroll
        for (int i = 0; i < 16; ++i) s += red[i][t];
        tot[t] = s;
    }
    __syncthreads();
    if (t == 0) {
        float s = 0.f;
        #pragma unroll
        for (int i = 0; i < 8; ++i) s += tot[i];
        out[B_TOT] = 0.001f * (s / (float)((size_t)B_TOT * NA));
    }
    if (t >= 8 && t < 16)
        out[B_TOT + 1 + (t - 8)] = tot[t] / (float)B_TOT;
}

extern "C" void kernel_launch(void* const* d_in, const int* in_sizes, int n_in,
                              void* d_out, int out_size, void* d_ws, size_t ws_size,
                              hipStream_t stream) {
    (void)in_sizes; (void)n_in; (void)out_size; (void)ws_size;
    const float* agent_qs = (const float*)d_in[0];
    const float* states   = (const float*)d_in[1];
    const int*   actions  = (const int*)d_in[2];
    const float* sel_W1   = (const float*)d_in[3];
    const float* sel_b1   = (const float*)d_in[4];
    const float* sel_W2   = (const float*)d_in[5];
    const float* key_W1   = (const float*)d_in[6];
    const float* key_b1   = (const float*)d_in[7];
    const float* key_W2   = (const float*)d_in[8];
    const float* wh_W1    = (const float*)d_in[9];
    const float* wh_b1    = (const float*)d_in[10];
    const float* wh_W2    = (const float*)d_in[11];
    const float* wh_b2    = (const float*)d_in[12];
    const float* v_W1     = (const float*)d_in[13];
    const float* v_b1     = (const float*)d_in[14];
    const float* v_W2     = (const float*)d_in[15];
    const float* v_b2     = (const float*)d_in[16];

    float* out = (float*)d_out;
    float* ws  = (float*)d_ws;
    ushort* h1bf  = (ushort*)(ws + WS_H1BF);
    ushort* m_buf = (ushort*)(ws + WS_MBF);
    float* lg_buf = ws + WS_LG;
    float* part   = ws + WS_PART;
    float* part2  = ws + WS_P2;
    ushort* Abf   = (ushort*)(ws + WS_ABF);
    ushort* Wbf   = (ushort*)(ws + WS_WBF);
    ushort* KW32  = (ushort*)(ws + WS_KW32);
    ushort* B2p   = (ushort*)(ws + WS_B2P);
    ushort* M2T   = (ushort*)(ws + WS_M2T);

    k_cvt_all<<<CVT_A_BLK + CVT_W_BLK + 4, 256, 0, stream>>>(
        states, sel_W1, wh_W1, v_W1, key_W1, key_b1, Abf, Wbf, KW32, B2p);
    k_m2<<<dim3(NH, KHID / 8), 256, 0, stream>>>(sel_W2, key_W2, M2T);
    k_gemm1_mfma<<<dim3(NTOT / 128, B_TOT / 128), 256, 0, stream>>>(
        Abf, Wbf, sel_b1, wh_b1, v_b1, h1bf);
    k_m_mfma<<<dim3(NH, B_TOT / 64), 256, 0, stream>>>(h1bf, M2T, m_buf);
    k_logits_mfma<<<dim3(B_TOT / 4), 256, 0, stream>>>(
        Abf, KW32, B2p, agent_qs, m_buf, lg_buf);
    k_softmax<<<dim3(B_TOT), 256, 0, stream>>>(
        lg_buf, agent_qs, actions, h1bf, wh_W2, wh_b2, v_W2, v_b2, out, part);
    k_final_s1<<<32, 256, 0, stream>>>(part, part2);
    k_final_s2<<<1, 256, 0, stream>>>(part2, out);
}